// Round 5
// baseline (157.360 us; speedup 1.0000x reference)
//
#include <hip/hip_runtime.h>
#include <hip/hip_bf16.h>

// Problem constants
#define CO    128
#define CI    128
#define NPIX  3136   // 56*56
#define PH    58
#define PPIX  3364   // 58*58
#define HPX4  348    // halo pixels per 4-row tile: 6 padded rows * 58
#define SROW2 144    // LDS bytes per halo pixel per ci-half: 128 data + 16 pad

typedef __bf16 bf16x8 __attribute__((ext_vector_type(8)));
typedef float  f32x4  __attribute__((ext_vector_type(4)));

// ---------------------------------------------------------------------------
// Fused prep: [0,2048) weights | [2048,2504) border zero | [2504,4072) transpose.
// it layout: [b][ci-half h][3364 px][64 ci].  (unchanged from round 3/4)
// ---------------------------------------------------------------------------
__global__ void prep_all(const float* __restrict__ in,
                         const float* __restrict__ eps,
                         const float* __restrict__ psi,
                         const float* __restrict__ mu,
                         __bf16* __restrict__ wt,
                         __bf16* __restrict__ it) {
  __shared__ __align__(16) char smem[32256];
  const int bx = blockIdx.x, tid = threadIdx.x;

  if (bx < 2048) {
    // ---- weights phase: block covers idx0..idx0+255 (one b, two co) ----
    float* Ebuf = (float*)smem;              // 2304 f32
    float* Pbuf = (float*)(smem + 9216);     // 2304 f32
    float* Mbuf = (float*)(smem + 18432);    // 2304 f32
    __bf16* Wb  = (__bf16*)(smem + 27648);   // [9][256] bf16
    const int idx0  = bx * 256;              // multiple of 256 -> ci0 = 0
    const int b     = idx0 >> 14;            // 64 blocks per b, no straddle
    const int coci0 = idx0 & 16383;          // co0*CI
    const f32x4* esrc = (const f32x4*)(eps + (size_t)idx0 * 9);
    const f32x4* psrc = (const f32x4*)(psi + (size_t)coci0 * 9);
    const f32x4* msrc = (const f32x4*)(mu  + (size_t)coci0 * 9);
#pragma unroll
    for (int i = 0; i < 3; ++i) {            // 576 f32x4 per array
      int j = i * 256 + tid;
      if (j < 576) {
        ((f32x4*)Ebuf)[j] = esrc[j];
        ((f32x4*)Pbuf)[j] = psrc[j];
        ((f32x4*)Mbuf)[j] = msrc[j];
      }
    }
    __syncthreads();
#pragma unroll
    for (int p = 0; p < 9; ++p) {
      float v = Ebuf[tid * 9 + p] * __expf(Pbuf[tid * 9 + p]) + Mbuf[tid * 9 + p];
      Wb[p * 256 + tid] = (__bf16)v;
    }
    __syncthreads();
    __bf16* wb = wt + (size_t)b * 9 * CO * CI + coci0;
#pragma unroll
    for (int i = 0; i < 2; ++i) {
      int s = i * 256 + tid;
      if (s < 288) {
        int p = s >> 5, j = s & 31;
        *(f32x4*)(wb + (size_t)p * CO * CI + j * 8) =
            *(const f32x4*)&Wb[p * 256 + j * 8];
      }
    }
  } else if (bx < 2504) {
    int cid = (bx - 2048) * 256 + tid;
    int pid = cid >> 4;
    int chunk = cid & 15;                    // 16 chunks of 16B per pixel
    int h  = chunk >> 3;                     // ci-half
    int c8 = chunk & 7;
    int b = pid / 228;
    int e = pid - b * 228;
    int ph, pw;
    if (e < 58)       { ph = 0;       pw = e; }
    else if (e < 116) { ph = 57;      pw = e - 58; }
    else if (e < 172) { ph = e - 115; pw = 0; }
    else              { ph = e - 171; pw = 57; }
    f32x4 z = {0.f, 0.f, 0.f, 0.f};
    *(f32x4*)&it[((size_t)(b * 2 + h) * PPIX + ph * PH + pw) * 64 + c8 * 8] = z;
  } else {
    __bf16 (*T)[136] = (__bf16(*)[136])smem;   // [64][136]
    int tx = bx - 2504;
    int b  = tx / 49;
    int p0 = (tx - b * 49) * 64;
    const float* src = in + (size_t)b * CI * NPIX;
#pragma unroll
    for (int jj = 0; jj < 8; ++jj) {
      int c = jj * 256 + tid;
      int ci = c >> 4, xc = c & 15;
      float4 v = *(const float4*)(src + (size_t)ci * NPIX + p0 + xc * 4);
      T[xc * 4 + 0][ci] = (__bf16)v.x;
      T[xc * 4 + 1][ci] = (__bf16)v.y;
      T[xc * 4 + 2][ci] = (__bf16)v.z;
      T[xc * 4 + 3][ci] = (__bf16)v.w;
    }
    __syncthreads();
#pragma unroll
    for (int jj = 0; jj < 4; ++jj) {
      int c = jj * 256 + tid;
      int pl = c >> 4, xc = c & 15;
      int h  = xc >> 3;
      int c8 = xc & 7;
      int pix = p0 + pl;
      int oh = pix / 56, ow = pix - oh * 56;
      int ppix = (oh + 1) * PH + (ow + 1);
      *(f32x4*)&it[((size_t)(b * 2 + h) * PPIX + ppix) * 64 + c8 * 8] =
          *(const f32x4*)&T[pl][xc * 8];
    }
  }
}

// ---------------------------------------------------------------------------
// GEMM/conv, 4-row tile / 64-co waves: doubled B-reuse, halved LDS volume.
//   block = 128 co x 224 n (4 image rows), 4 waves = 2 cg(64co) x 2 ng(112n).
//   Each wave: 4 m-frags x 7 n-frags = 28 MFMA/step -> each 1KB B LDS read
//   feeds 4 MFMAs (was 2).  Halo per ci-half: 6 padded rows x 58 px x 144B
//   = 50.1KB LDS.  K-loop = 2 halves x 18 steps, restage at midpoint (only
//   2 in-loop barriers).  A: global->VGPR distance-2 ring; setprio around
//   MFMA cluster.  Grid 14 tiles x 32 batch = 448 blocks (1.75/CU, single
//   pass; registers up to 2 waves/SIMD are free since grid binds occupancy).
// ---------------------------------------------------------------------------
__global__ __launch_bounds__(256, 2) void bconv_gemm(
    const __bf16* __restrict__ wt,   // [b][9][128 co][128 ci]
    const __bf16* __restrict__ it,   // [b][2 h][3364 px][64 ci]
    float* __restrict__ out) {       // [b][128 co][3136 n]
  __shared__ __align__(16) char Bsh[HPX4 * SROW2];   // 50112 B
  const int tid  = threadIdx.x;
  const int w    = tid >> 6;
  const int lane = tid & 63;
  const int quad = lane >> 4;
  const int l15  = lane & 15;
  const int cg   = w & 1;            // co-group: co [cg*64, cg*64+64)
  const int ng   = w >> 1;           // n-group: rows [ng*2, ng*2+2) of the tile

  // Decode: lin = x + 8*(tile*4 + bhi); b = x + 8*bhi -> same-b blocks share an XCD
  const int lin = blockIdx.x;
  const int x   = lin & 7;
  const int j   = lin >> 3;          // 0..55
  const int bhi = j & 3;
  const int tile = j >> 2;           // 0..13
  const int b   = x + 8 * bhi;
  const int oh0 = tile * 4;          // first output row of this tile

  // ---- halo staging, ci-half 0: 348 px x 8 chunks of 16B = 2784 chunks ----
  const __bf16* hsrc0 = it + ((size_t)(b * 2 + 0) * PPIX + oh0 * PH) * 64;
  const __bf16* hsrc1 = it + ((size_t)(b * 2 + 1) * PPIX + oh0 * PH) * 64;
#pragma unroll
  for (int i = 0; i < 11; ++i) {
    int idx = i * 256 + tid;
    if (idx < HPX4 * 8) {
      int px = idx >> 3, sub = idx & 7;
      *(f32x4*)&Bsh[px * SROW2 + sub * 16] = *(const f32x4*)(hsrc0 + (size_t)idx * 8);
    }
  }
  __syncthreads();

  // ---- per-lane B fragment LDS byte-bases (tap (0,0), kk=0) ----
  int bbase[7];
#pragma unroll
  for (int nf = 0; nf < 7; ++nf) {
    int n = nf * 16 + l15;                   // 0..111 within this ng-half
    int hi = (n >= 56) ? 1 : 0;
    int r = ng * 2 + hi;                     // output row within tile, 0..3
    int c = n - hi * 56;
    bbase[nf] = (r * PH + c) * SROW2 + quad * 16;
  }

  // ---- per-lane A global bases (elements), 4 m-frags of 16 co ----
  const int co0 = cg * 64;
  const __bf16* wtb = wt + (size_t)b * 9 * CO * CI;
  int ab[4];
#pragma unroll
  for (int mf = 0; mf < 4; ++mf)
    ab[mf] = (co0 + mf * 16 + l15) * CI + quad * 8;

  f32x4 acc[4][7] = {};
  // distance-2 A-prefetch ring (statically indexed under full unroll)
  // step t: h = t/18, s2 = t%18, p = s2>>1, kk = s2&1; A off = p*CO*CI + h*64 + kk*32
  bf16x8 areg[3][4];
#pragma unroll
  for (int mf = 0; mf < 4; ++mf) areg[0][mf] = *(const bf16x8*)(wtb + ab[mf]);
#pragma unroll
  for (int mf = 0; mf < 4; ++mf) areg[1][mf] = *(const bf16x8*)(wtb + 32 + ab[mf]);

#pragma unroll
  for (int s = 0; s < 36; ++s) {
    if (s == 18) {
      __syncthreads();                       // all waves done reading half 0
#pragma unroll
      for (int i = 0; i < 11; ++i) {
        int idx = i * 256 + tid;
        if (idx < HPX4 * 8) {
          int px = idx >> 3, sub = idx & 7;
          *(f32x4*)&Bsh[px * SROW2 + sub * 16] = *(const f32x4*)(hsrc1 + (size_t)idx * 8);
        }
      }
      __syncthreads();
    }
    // prefetch A for step s+2
    if (s < 34) {
      const int tn  = s + 2;
      const int hn  = tn / 18;
      const int s2n = tn % 18;
      const int pn  = s2n >> 1;
      const int kkn = s2n & 1;
      const __bf16* ap = wtb + pn * (CO * CI) + hn * 64 + kkn * 32;
#pragma unroll
      for (int mf = 0; mf < 4; ++mf)
        areg[tn % 3][mf] = *(const bf16x8*)(ap + ab[mf]);
    }
    const int s2 = s % 18;
    const int p  = s2 >> 1;
    const int kk = s2 & 1;
    const int kh = p / 3, kw = p - kh * 3;
    const int tapb = (kh * PH + kw) * SROW2 + kk * 64;   // compile-time (unrolled)
    __builtin_amdgcn_s_setprio(1);
#pragma unroll
    for (int nf = 0; nf < 7; ++nf) {
      bf16x8 bfr = *(const bf16x8*)&Bsh[bbase[nf] + tapb];
#pragma unroll
      for (int mf = 0; mf < 4; ++mf)
        acc[mf][nf] = __builtin_amdgcn_mfma_f32_16x16x32_bf16(areg[s % 3][mf], bfr, acc[mf][nf], 0, 0, 0);
    }
    __builtin_amdgcn_s_setprio(0);
  }

  // ---- epilogue: col(l15)=n, row(quad*4+r)=co; n_glob = oh0*56 + ng*112 + n ----
  float* ob = out + (size_t)b * CO * NPIX + oh0 * 56 + ng * 112;
#pragma unroll
  for (int mf = 0; mf < 4; ++mf) {
#pragma unroll
    for (int nf = 0; nf < 7; ++nf) {
#pragma unroll
      for (int r = 0; r < 4; ++r) {
        int co = co0 + mf * 16 + quad * 4 + r;
        ob[(size_t)co * NPIX + nf * 16 + l15] = acc[mf][nf][r];
      }
    }
  }
}

// ---------------------------------------------------------------------------
extern "C" void kernel_launch(void* const* d_in, const int* in_sizes, int n_in,
                              void* d_out, int out_size, void* d_ws, size_t ws_size,
                              hipStream_t stream) {
  const float* inp = (const float*)d_in[0];   // [32,128,56,56]
  const float* eps = (const float*)d_in[1];   // [32,128,128,3,3]
  const float* psi = (const float*)d_in[2];   // [128,128,3,3]
  const float* mu  = (const float*)d_in[3];   // [128,128,3,3]

  // ws layout: wt (9,437,184 B) | it (27,557,888 B)
  __bf16* wt = (__bf16*)d_ws;
  __bf16* it = (__bf16*)((char*)d_ws + 9437184);

  prep_all<<<4072, 256, 0, stream>>>(inp, eps, psi, mu, wt, it);
  bconv_gemm<<<448, 256, 0, stream>>>(wt, it, (float*)d_out);
}